// Round 5
// baseline (534.045 us; speedup 1.0000x reference)
//
#include <hip/hip_runtime.h>
#include <math.h>

#define NN 50000
#define EE 800000
#define GG 256
#define NB_SCAN 196   // ceil(50000/256)

__device__ __forceinline__ float gelu_f(float v){
    return 0.5f * v * (1.0f + erff(v * 0.70710678118654752f));
}

// ---------------- degree count over dst ----------------
__global__ __launch_bounds__(256) void k_deg(const int* __restrict__ dst, int* __restrict__ deg, int e){
    int i = blockIdx.x * blockDim.x + threadIdx.x;
    if (i < e) atomicAdd(&deg[dst[i]], 1);
}

// ---------------- scan phase 1: per-block sums ----------------
__global__ __launch_bounds__(256) void k_bsum(const int* __restrict__ deg, int* __restrict__ bsum, int n){
    __shared__ int s[256];
    int t = threadIdx.x;
    int i = blockIdx.x * 256 + t;
    s[t] = (i < n) ? deg[i] : 0;
    __syncthreads();
    for (int off = 128; off > 0; off >>= 1){
        if (t < off) s[t] += s[t + off];
        __syncthreads();
    }
    if (t == 0) bsum[blockIdx.x] = s[0];
}

// ---------------- scan phase 2: single-block scan of partials ----------------
__global__ __launch_bounds__(256) void k_pscan(const int* __restrict__ bsum, int* __restrict__ boff,
                                               int* __restrict__ rp, int nb, int n){
    __shared__ int s[256];
    int t = threadIdx.x;
    int v = (t < nb) ? bsum[t] : 0;
    s[t] = v;
    __syncthreads();
    for (int off = 1; off < 256; off <<= 1){
        int u = (t >= off) ? s[t - off] : 0;
        __syncthreads();
        s[t] += u;
        __syncthreads();
    }
    if (t < nb) boff[t] = s[t] - v;          // exclusive block offset
    if (t == nb - 1) rp[n] = s[t];           // total (= E)
}

// ---------------- scan phase 3: apply ----------------
__global__ __launch_bounds__(256) void k_apply(const int* __restrict__ deg, const int* __restrict__ boff,
                                               int* __restrict__ rp, int* __restrict__ cursor,
                                               float* __restrict__ dis, int n){
    __shared__ int s[256];
    int t = threadIdx.x;
    int i = blockIdx.x * 256 + t;
    int d = (i < n) ? deg[i] : 0;
    s[t] = d;
    __syncthreads();
    for (int off = 1; off < 256; off <<= 1){
        int u = (t >= off) ? s[t - off] : 0;
        __syncthreads();
        s[t] += u;
        __syncthreads();
    }
    if (i < n){
        int excl = s[t] - d + boff[blockIdx.x];
        rp[i] = excl;
        cursor[i] = excl;
        dis[i] = rsqrtf((float)(d + 1));     // +1 self loop
    }
}

// ---------------- CSR fill ----------------
__global__ __launch_bounds__(256) void k_fill(const int* __restrict__ src, const int* __restrict__ dst,
                                              const float* __restrict__ dis, int* __restrict__ cursor,
                                              int* __restrict__ col, float* __restrict__ wn, int e){
    int i = blockIdx.x * blockDim.x + threadIdx.x;
    if (i < e){
        int d = dst[i], s = src[i];
        int p = atomicAdd(&cursor[d], 1);
        col[p] = s;
        wn[p]  = dis[s] * dis[d];
    }
}

// ---------------- layer-1 aggregation of x (C=1): edge-parallel atomics + self loop ----------------
__global__ __launch_bounds__(256) void k_agg1(const float* __restrict__ x, const int* __restrict__ src,
                                              const int* __restrict__ dst, const float* __restrict__ dis,
                                              float* __restrict__ agg, int e, int n){
    int i = blockIdx.x * blockDim.x + threadIdx.x;
    if (i < e){
        int s = src[i], d = dst[i];
        atomicAdd(&agg[d], x[s] * dis[s] * dis[d]);
    } else if (i < e + n){
        int node = i - e;
        float dn = dis[node];
        atomicAdd(&agg[node], dn * dn * x[node]);
    }
}

// ---------------- gather with inline BN of previous layer (float4, 4-edge unroll) ----------------
template<int C>
__global__ __launch_bounds__(256) void k_gather(const float* __restrict__ h, const int* __restrict__ rp,
                                                const int* __restrict__ col, const float* __restrict__ wn,
                                                const float* __restrict__ dis, const float* __restrict__ stat,
                                                const float* __restrict__ gamma, const float* __restrict__ beta,
                                                float* __restrict__ outp, int n){
    constexpr int TPN = C / 4;
    int i = blockIdx.x * 256 + threadIdx.x;
    int node = i / TPN, q = i % TPN;
    if (node >= n) return;
    int c0 = q * 4;
    const float invn = 1.0f / (float)NN;
    float scv[4], shv[4];
#pragma unroll
    for (int u = 0; u < 4; u++){
        float mean = stat[c0 + u] * invn;
        float var  = stat[128 + c0 + u] * invn - mean * mean;
        float sc   = gamma[c0 + u] * rsqrtf(var + 1e-5f);
        scv[u] = sc;
        shv[u] = beta[c0 + u] - mean * sc;
    }
    const float4* h4 = (const float4*)h;
    int beg = rp[node], end = rp[node + 1];
    float a0 = 0.f, a1 = 0.f, a2 = 0.f, a3 = 0.f;   // raw weighted sums (BN applied affinely at end)
    float b0 = 0.f, b1 = 0.f, b2 = 0.f, b3 = 0.f;
    float wsum_a = 0.f, wsum_b = 0.f;
    int j = beg;
    for (; j + 3 < end; j += 4){
        int   i0 = col[j], i1 = col[j+1], i2 = col[j+2], i3 = col[j+3];
        float w0 = wn[j], w1 = wn[j+1], w2 = wn[j+2], w3 = wn[j+3];
        float4 v0 = h4[i0 * TPN + q];
        float4 v1 = h4[i1 * TPN + q];
        float4 v2 = h4[i2 * TPN + q];
        float4 v3 = h4[i3 * TPN + q];
        a0 += v0.x*w0; a1 += v0.y*w0; a2 += v0.z*w0; a3 += v0.w*w0; wsum_a += w0;
        b0 += v1.x*w1; b1 += v1.y*w1; b2 += v1.z*w1; b3 += v1.w*w1; wsum_b += w1;
        a0 += v2.x*w2; a1 += v2.y*w2; a2 += v2.z*w2; a3 += v2.w*w2; wsum_a += w2;
        b0 += v3.x*w3; b1 += v3.y*w3; b2 += v3.z*w3; b3 += v3.w*w3; wsum_b += w3;
    }
    for (; j < end; j++){
        float w = wn[j];
        float4 v = h4[col[j] * TPN + q];
        a0 += v.x*w; a1 += v.y*w; a2 += v.z*w; a3 += v.w*w; wsum_a += w;
    }
    float dn = dis[node];
    float ws = dn * dn;
    float4 vs = h4[node * TPN + q];
    a0 += vs.x*ws; a1 += vs.y*ws; a2 += vs.z*ws; a3 += vs.w*ws; wsum_a += ws;
    a0 += b0; a1 += b1; a2 += b2; a3 += b3;
    float wsum = wsum_a + wsum_b;
    float4 r = make_float4(a0 * scv[0] + shv[0] * wsum,
                           a1 * scv[1] + shv[1] * wsum,
                           a2 * scv[2] + shv[2] * wsum,
                           a3 * scv[3] + shv[3] * wsum);
    ((float4*)outp)[node * TPN + q] = r;
}

// ---------------- 1->16 linear + bias + GELU (x is a single channel) ----------------
__global__ __launch_bounds__(256) void k_lin1(const float* __restrict__ xin, const float* __restrict__ W,
                                              const float* __restrict__ bias, float* __restrict__ outp, int n){
    int i = blockIdx.x * 256 + threadIdx.x;
    int node = i / 16, c = i % 16;
    if (node >= n) return;
    outp[i] = gelu_f(bias[c] + xin[node] * W[c]);
}

// ---------------- register-blocked dense: 4 nodes x 4 channels per thread ----------------
// POOL=false: outp[node*COUT+c] = gelu(acc).  POOL=true: atomic mean-pool epilogue.
template<int CIN, int COUT, bool POOL>
__global__ __launch_bounds__(256) void k_lin4(const float* __restrict__ xin, const float* __restrict__ W,
                                              const float* __restrict__ bias, float* __restrict__ outp,
                                              const int* __restrict__ batch, float* __restrict__ pool,
                                              float* __restrict__ cnt, int n){
    constexpr int QC = COUT / 4;      // float4 channel groups
    constexpr int K4 = CIN / 4;       // float4 K groups
    long long i = (long long)blockIdx.x * 256 + threadIdx.x;
    int tile = (int)(i / QC), q = (int)(i % QC);
    int n0 = tile * 4;
    if (n0 >= n) return;               // NN % 4 == 0, so full tiles only
    const float4* x4 = (const float4*)xin;
    const float4* W4 = (const float4*)W;
    float4 bb = ((const float4*)bias)[q];
    float acc[4][4];
#pragma unroll
    for (int nd = 0; nd < 4; nd++){
        acc[nd][0] = bb.x; acc[nd][1] = bb.y; acc[nd][2] = bb.z; acc[nd][3] = bb.w;
    }
#pragma unroll
    for (int k4 = 0; k4 < K4; k4++){
        float xr[4][4];
#pragma unroll
        for (int nd = 0; nd < 4; nd++){
            float4 t = x4[(long long)(n0 + nd) * K4 + k4];
            xr[nd][0] = t.x; xr[nd][1] = t.y; xr[nd][2] = t.z; xr[nd][3] = t.w;
        }
        float wr[4][4];
#pragma unroll
        for (int j = 0; j < 4; j++){
            float4 t = W4[(long long)(k4 * 4 + j) * QC + q];
            wr[j][0] = t.x; wr[j][1] = t.y; wr[j][2] = t.z; wr[j][3] = t.w;
        }
#pragma unroll
        for (int nd = 0; nd < 4; nd++)
#pragma unroll
            for (int j = 0; j < 4; j++)
#pragma unroll
                for (int c = 0; c < 4; c++)
                    acc[nd][c] += xr[nd][j] * wr[j][c];
    }
    if (!POOL){
        float4* o4 = (float4*)outp;
#pragma unroll
        for (int nd = 0; nd < 4; nd++){
            o4[(long long)(n0 + nd) * QC + q] =
                make_float4(gelu_f(acc[nd][0]), gelu_f(acc[nd][1]),
                            gelu_f(acc[nd][2]), gelu_f(acc[nd][3]));
        }
    } else {
        int cur = batch[n0];
        float p0 = 0.f, p1 = 0.f, p2 = 0.f, p3 = 0.f, cloc = 0.f;
        int c0 = q * 4;
#pragma unroll
        for (int nd = 0; nd < 4; nd++){
            int gr = batch[n0 + nd];
            if (gr != cur){
                atomicAdd(&pool[cur * COUT + c0 + 0], p0);
                atomicAdd(&pool[cur * COUT + c0 + 1], p1);
                atomicAdd(&pool[cur * COUT + c0 + 2], p2);
                atomicAdd(&pool[cur * COUT + c0 + 3], p3);
                if (q == 0) atomicAdd(&cnt[cur], cloc);
                p0 = p1 = p2 = p3 = 0.f; cloc = 0.f; cur = gr;
            }
            p0 += gelu_f(acc[nd][0]); p1 += gelu_f(acc[nd][1]);
            p2 += gelu_f(acc[nd][2]); p3 += gelu_f(acc[nd][3]);
            cloc += 1.f;
        }
        atomicAdd(&pool[cur * COUT + c0 + 0], p0);
        atomicAdd(&pool[cur * COUT + c0 + 1], p1);
        atomicAdd(&pool[cur * COUT + c0 + 2], p2);
        atomicAdd(&pool[cur * COUT + c0 + 3], p3);
        if (q == 0) atomicAdd(&cnt[cur], cloc);
    }
}

// ---------------- BN stats: 128-block grid-stride streaming reduction ----------------
template<int C>
__global__ __launch_bounds__(256) void k_stats(const float* __restrict__ h, float* __restrict__ stat, int n){
    constexpr int REP = 256 / C;
    int t = threadIdx.x;
    int rep = t / C;
    int c = t % C;
    float s = 0.f, q = 0.f;
    for (int row = blockIdx.x * REP + rep; row < n; row += gridDim.x * REP){
        float v = h[(long long)row * C + c];
        s += v; q += v * v;
    }
    __shared__ float ss[256], sq[256];
    ss[t] = s; sq[t] = q;
    __syncthreads();
    for (int off = 128; off >= C; off >>= 1){
        if (t < off){ ss[t] += ss[t + off]; sq[t] += sq[t + off]; }
        __syncthreads();
    }
    if (t < C){
        atomicAdd(&stat[t], ss[t]);
        atomicAdd(&stat[128 + t], sq[t]);
    }
}

// ---------------- MLP head: 256 graphs, one block each ----------------
__global__ __launch_bounds__(128) void k_mlp(const float* __restrict__ pool, const float* __restrict__ cnt,
                                             const float* __restrict__ yex,
                                             const float* __restrict__ lw1, const float* __restrict__ lb1,
                                             const float* __restrict__ lw2, const float* __restrict__ lb2,
                                             const float* __restrict__ lw3, const float* __restrict__ lb3,
                                             const float* __restrict__ lw4, const float* __restrict__ lb4,
                                             float* __restrict__ outp){
    int g = blockIdx.x;
    int t = threadIdx.x;
    __shared__ float z[136];
    __shared__ float z2[128];
    __shared__ float z3[64];
    __shared__ float z4[32];
    float cdiv = fmaxf(cnt[g], 1.0f);
    z[t] = pool[g * 128 + t] / cdiv;
    if (t < 7) z[128 + t] = yex[g * 7 + t];
    __syncthreads();
    {   // 135 -> 128
        float acc = lb1[t];
        for (int k = 0; k < 135; k++) acc += z[k] * lw1[k * 128 + t];
        z2[t] = gelu_f(acc);
    }
    __syncthreads();
    if (t < 64){   // 128 -> 64
        float acc = lb2[t];
        for (int k = 0; k < 128; k++) acc += z2[k] * lw2[k * 64 + t];
        z3[t] = gelu_f(acc);
    }
    __syncthreads();
    if (t < 32){   // 64 -> 32
        float acc = lb3[t];
        for (int k = 0; k < 64; k++) acc += z3[k] * lw3[k * 32 + t];
        z4[t] = gelu_f(acc);
    }
    __syncthreads();
    if (t < 2){    // 32 -> 2, sigmoid
        float acc = lb4[t];
        for (int k = 0; k < 32; k++) acc += z4[k] * lw4[k * 2 + t];
        outp[g * 2 + t] = 1.0f / (1.0f + expf(-acc));
    }
}

extern "C" void kernel_launch(void* const* d_in, const int* in_sizes, int n_in,
                              void* d_out, int out_size, void* d_ws, size_t ws_size,
                              hipStream_t stream) {
    const float* x     = (const float*)d_in[0];
    const int*   ei    = (const int*)  d_in[1];   // [2, E]: src = ei, dst = ei+E
    const int*   batch = (const int*)  d_in[2];
    const float* yex   = (const float*)d_in[3];
    const float* W1 = (const float*)d_in[4];  const float* b1 = (const float*)d_in[5];
    const float* W2 = (const float*)d_in[6];  const float* b2 = (const float*)d_in[7];
    const float* W3 = (const float*)d_in[8];  const float* b3 = (const float*)d_in[9];
    const float* W4 = (const float*)d_in[10]; const float* b4 = (const float*)d_in[11];
    const float* g1 = (const float*)d_in[12]; const float* be1 = (const float*)d_in[13];
    const float* g2 = (const float*)d_in[14]; const float* be2 = (const float*)d_in[15];
    const float* g3 = (const float*)d_in[16]; const float* be3 = (const float*)d_in[17];
    const float* lw1 = (const float*)d_in[18]; const float* lb1 = (const float*)d_in[19];
    const float* lw2 = (const float*)d_in[20]; const float* lb2 = (const float*)d_in[21];
    const float* lw3 = (const float*)d_in[22]; const float* lb3 = (const float*)d_in[23];
    const float* lw4 = (const float*)d_in[24]; const float* lb4 = (const float*)d_in[25];
    float* out = (float*)d_out;

    // ---- workspace carve (256B-aligned); zero-region first ----
    char* wsb = (char*)d_ws;
    size_t off = 0;
    auto alloc = [&](size_t elems) -> void* {
        void* p = wsb + off;
        off += ((elems * 4 + 255) / 256) * 256;
        return p;
    };
    int*   deg    = (int*)  alloc(NN);
    float* stats  = (float*)alloc(3 * 256);      // layer l: [l*256+c]=sum, [l*256+128+c]=sumsq
    float* pool   = (float*)alloc(GG * 128);
    float* cntv   = (float*)alloc(GG);
    float* agg1   = (float*)alloc(NN);
    size_t zero_bytes = off;
    int*   rp     = (int*)  alloc(NN + 1);
    int*   cursor = (int*)  alloc(NN);
    float* dis    = (float*)alloc(NN);
    int*   bsum   = (int*)  alloc(NB_SCAN);
    int*   boff   = (int*)  alloc(NB_SCAN);
    int*   col    = (int*)  alloc(EE);
    float* wn     = (float*)alloc(EE);
    float* hbuf   = (float*)alloc((size_t)NN * 64);   // raw gelu outputs (<=64 ch)
    float* abuf   = (float*)alloc((size_t)NN * 64);   // aggregated inputs (<=64 ch)

    hipMemsetAsync(d_ws, 0, zero_bytes, stream);

    auto nb = [](long long total){ return (int)((total + 255) / 256); };

    // ---- graph norm precompute (parallel scan) ----
    k_deg  <<<nb(EE), 256, 0, stream>>>(ei + EE, deg, EE);
    k_bsum <<<NB_SCAN, 256, 0, stream>>>(deg, bsum, NN);
    k_pscan<<<1, 256, 0, stream>>>(bsum, boff, rp, NB_SCAN, NN);
    k_apply<<<NB_SCAN, 256, 0, stream>>>(deg, boff, rp, cursor, dis, NN);
    k_fill <<<nb(EE), 256, 0, stream>>>(ei, ei + EE, dis, cursor, col, wn, EE);

    // ---- layer 1: aggregate x (C=1), 1->16 linear+gelu, stats ----
    k_agg1<<<nb(EE + NN), 256, 0, stream>>>(x, ei, ei + EE, dis, agg1, EE, NN);
    k_lin1<<<nb((long long)NN * 16), 256, 0, stream>>>(agg1, W1, b1, hbuf, NN);
    k_stats<16><<<128, 256, 0, stream>>>(hbuf, stats + 0, NN);

    // ---- layer 2: gather h1 (BN1 inline), 16->32 reg-blocked linear+gelu, stats ----
    k_gather<16><<<nb((long long)NN * 4), 256, 0, stream>>>(hbuf, rp, col, wn, dis, stats + 0, g1, be1, abuf, NN);
    k_lin4<16, 32, false><<<nb((long long)(NN / 4) * 8), 256, 0, stream>>>(abuf, W2, b2, hbuf, nullptr, nullptr, nullptr, NN);
    k_stats<32><<<128, 256, 0, stream>>>(hbuf, stats + 256, NN);

    // ---- layer 3: gather h2 (BN2 inline), 32->64 reg-blocked linear+gelu, stats ----
    k_gather<32><<<nb((long long)NN * 8), 256, 0, stream>>>(hbuf, rp, col, wn, dis, stats + 256, g2, be2, abuf, NN);
    k_lin4<32, 64, false><<<nb((long long)(NN / 4) * 16), 256, 0, stream>>>(abuf, W3, b3, hbuf, nullptr, nullptr, nullptr, NN);
    k_stats<64><<<128, 256, 0, stream>>>(hbuf, stats + 512, NN);

    // ---- layer 4: gather h3 (BN3 inline), fused 64->128 reg-blocked linear+gelu+pool ----
    k_gather<64><<<nb((long long)NN * 16), 256, 0, stream>>>(hbuf, rp, col, wn, dis, stats + 512, g3, be3, abuf, NN);
    k_lin4<64, 128, true><<<nb((long long)(NN / 4) * 32), 256, 0, stream>>>(abuf, W4, b4, nullptr, batch, pool, cntv, NN);

    // ---- MLP head ----
    k_mlp<<<GG, 128, 0, stream>>>(pool, cntv, yex,
                                  lw1, lb1, lw2, lb2, lw3, lb3, lw4, lb4, out);
}

// Round 6
// 471.695 us; speedup vs baseline: 1.1322x; 1.1322x over previous
//
#include <hip/hip_runtime.h>
#include <math.h>

#define NN 50000
#define EE 800000
#define GG 256
#define NB_SCAN 196   // ceil(50000/256)

__device__ __forceinline__ float gelu_f(float v){
    return 0.5f * v * (1.0f + erff(v * 0.70710678118654752f));
}

// ---------------- degree count over dst ----------------
__global__ __launch_bounds__(256) void k_deg(const int* __restrict__ dst, int* __restrict__ deg, int e){
    int i = blockIdx.x * blockDim.x + threadIdx.x;
    if (i < e) atomicAdd(&deg[dst[i]], 1);
}

// ---------------- scan phase 1: per-block sums ----------------
__global__ __launch_bounds__(256) void k_bsum(const int* __restrict__ deg, int* __restrict__ bsum, int n){
    __shared__ int s[256];
    int t = threadIdx.x;
    int i = blockIdx.x * 256 + t;
    s[t] = (i < n) ? deg[i] : 0;
    __syncthreads();
    for (int off = 128; off > 0; off >>= 1){
        if (t < off) s[t] += s[t + off];
        __syncthreads();
    }
    if (t == 0) bsum[blockIdx.x] = s[0];
}

// ---------------- scan phase 2: single-block scan of partials ----------------
__global__ __launch_bounds__(256) void k_pscan(const int* __restrict__ bsum, int* __restrict__ boff,
                                               int* __restrict__ rp, int nb, int n){
    __shared__ int s[256];
    int t = threadIdx.x;
    int v = (t < nb) ? bsum[t] : 0;
    s[t] = v;
    __syncthreads();
    for (int off = 1; off < 256; off <<= 1){
        int u = (t >= off) ? s[t - off] : 0;
        __syncthreads();
        s[t] += u;
        __syncthreads();
    }
    if (t < nb) boff[t] = s[t] - v;          // exclusive block offset
    if (t == nb - 1) rp[n] = s[t];           // total (= E)
}

// ---------------- scan phase 3: apply ----------------
__global__ __launch_bounds__(256) void k_apply(const int* __restrict__ deg, const int* __restrict__ boff,
                                               int* __restrict__ rp, int* __restrict__ cursor,
                                               float* __restrict__ dis, int n){
    __shared__ int s[256];
    int t = threadIdx.x;
    int i = blockIdx.x * 256 + t;
    int d = (i < n) ? deg[i] : 0;
    s[t] = d;
    __syncthreads();
    for (int off = 1; off < 256; off <<= 1){
        int u = (t >= off) ? s[t - off] : 0;
        __syncthreads();
        s[t] += u;
        __syncthreads();
    }
    if (i < n){
        int excl = s[t] - d + boff[blockIdx.x];
        rp[i] = excl;
        cursor[i] = excl;
        dis[i] = rsqrtf((float)(d + 1));     // +1 self loop
    }
}

// ---------------- CSR fill ----------------
__global__ __launch_bounds__(256) void k_fill(const int* __restrict__ src, const int* __restrict__ dst,
                                              const float* __restrict__ dis, int* __restrict__ cursor,
                                              int* __restrict__ col, float* __restrict__ wn, int e){
    int i = blockIdx.x * blockDim.x + threadIdx.x;
    if (i < e){
        int d = dst[i], s = src[i];
        int p = atomicAdd(&cursor[d], 1);
        col[p] = s;
        wn[p]  = dis[s] * dis[d];
    }
}

// ---------------- layer-1 aggregation of x (C=1): edge-parallel atomics + self loop ----------------
__global__ __launch_bounds__(256) void k_agg1(const float* __restrict__ x, const int* __restrict__ src,
                                              const int* __restrict__ dst, const float* __restrict__ dis,
                                              float* __restrict__ agg, int e, int n){
    int i = blockIdx.x * blockDim.x + threadIdx.x;
    if (i < e){
        int s = src[i], d = dst[i];
        atomicAdd(&agg[d], x[s] * dis[s] * dis[d]);
    } else if (i < e + n){
        int node = i - e;
        float dn = dis[node];
        atomicAdd(&agg[node], dn * dn * x[node]);
    }
}

// ---------------- gather with inline BN of previous layer (float4, 4-edge unroll) ----------------
template<int C>
__global__ __launch_bounds__(256) void k_gather(const float* __restrict__ h, const int* __restrict__ rp,
                                                const int* __restrict__ col, const float* __restrict__ wn,
                                                const float* __restrict__ dis, const float* __restrict__ stat,
                                                const float* __restrict__ gamma, const float* __restrict__ beta,
                                                float* __restrict__ outp, int n){
    constexpr int TPN = C / 4;
    int i = blockIdx.x * 256 + threadIdx.x;
    int node = i / TPN, q = i % TPN;
    if (node >= n) return;
    int c0 = q * 4;
    const float invn = 1.0f / (float)NN;
    float scv[4], shv[4];
#pragma unroll
    for (int u = 0; u < 4; u++){
        float mean = stat[c0 + u] * invn;
        float var  = stat[128 + c0 + u] * invn - mean * mean;
        float sc   = gamma[c0 + u] * rsqrtf(var + 1e-5f);
        scv[u] = sc;
        shv[u] = beta[c0 + u] - mean * sc;
    }
    const float4* h4 = (const float4*)h;
    int beg = rp[node], end = rp[node + 1];
    float a0 = 0.f, a1 = 0.f, a2 = 0.f, a3 = 0.f;   // raw weighted sums (BN applied affinely at end)
    float b0 = 0.f, b1 = 0.f, b2 = 0.f, b3 = 0.f;
    float wsum_a = 0.f, wsum_b = 0.f;
    int j = beg;
    for (; j + 3 < end; j += 4){
        int   i0 = col[j], i1 = col[j+1], i2 = col[j+2], i3 = col[j+3];
        float w0 = wn[j], w1 = wn[j+1], w2 = wn[j+2], w3 = wn[j+3];
        float4 v0 = h4[i0 * TPN + q];
        float4 v1 = h4[i1 * TPN + q];
        float4 v2 = h4[i2 * TPN + q];
        float4 v3 = h4[i3 * TPN + q];
        a0 += v0.x*w0; a1 += v0.y*w0; a2 += v0.z*w0; a3 += v0.w*w0; wsum_a += w0;
        b0 += v1.x*w1; b1 += v1.y*w1; b2 += v1.z*w1; b3 += v1.w*w1; wsum_b += w1;
        a0 += v2.x*w2; a1 += v2.y*w2; a2 += v2.z*w2; a3 += v2.w*w2; wsum_a += w2;
        b0 += v3.x*w3; b1 += v3.y*w3; b2 += v3.z*w3; b3 += v3.w*w3; wsum_b += w3;
    }
    for (; j < end; j++){
        float w = wn[j];
        float4 v = h4[col[j] * TPN + q];
        a0 += v.x*w; a1 += v.y*w; a2 += v.z*w; a3 += v.w*w; wsum_a += w;
    }
    float dn = dis[node];
    float ws = dn * dn;
    float4 vs = h4[node * TPN + q];
    a0 += vs.x*ws; a1 += vs.y*ws; a2 += vs.z*ws; a3 += vs.w*ws; wsum_a += ws;
    a0 += b0; a1 += b1; a2 += b2; a3 += b3;
    float wsum = wsum_a + wsum_b;
    float4 r = make_float4(a0 * scv[0] + shv[0] * wsum,
                           a1 * scv[1] + shv[1] * wsum,
                           a2 * scv[2] + shv[2] * wsum,
                           a3 * scv[3] + shv[3] * wsum);
    ((float4*)outp)[node * TPN + q] = r;
}

// ---------------- 1->16 linear + bias + GELU (x is a single channel) ----------------
__global__ __launch_bounds__(256) void k_lin1(const float* __restrict__ xin, const float* __restrict__ W,
                                              const float* __restrict__ bias, float* __restrict__ outp, int n){
    int i = blockIdx.x * 256 + threadIdx.x;
    int node = i / 16, c = i % 16;
    if (node >= n) return;
    outp[i] = gelu_f(bias[c] + xin[node] * W[c]);
}

// ---------------- register-blocked dense: 4 nodes x 4 channels per thread ----------------
// __launch_bounds__(256, 4): cap VGPRs ~128 (round-5 post-mortem: uncapped -> 256 VGPR,
// 9% occupancy, scratch spill, 140us). Partial unroll keeps in-flight loads bounded.
template<int CIN, int COUT, bool POOL>
__global__ __launch_bounds__(256, 4) void k_lin4(const float* __restrict__ xin, const float* __restrict__ W,
                                              const float* __restrict__ bias, float* __restrict__ outp,
                                              const int* __restrict__ batch, float* __restrict__ pool,
                                              float* __restrict__ cnt, int n){
    constexpr int QC = COUT / 4;      // float4 channel groups
    constexpr int K4 = CIN / 4;       // float4 K groups
    long long i = (long long)blockIdx.x * 256 + threadIdx.x;
    int tile = (int)(i / QC), q = (int)(i % QC);
    int n0 = tile * 4;
    if (n0 >= n) return;               // NN % 4 == 0, so full tiles only
    const float4* x4 = (const float4*)xin;
    const float4* W4 = (const float4*)W;
    float4 bb = ((const float4*)bias)[q];
    float acc[4][4];
#pragma unroll
    for (int nd = 0; nd < 4; nd++){
        acc[nd][0] = bb.x; acc[nd][1] = bb.y; acc[nd][2] = bb.z; acc[nd][3] = bb.w;
    }
#pragma unroll 2
    for (int k4 = 0; k4 < K4; k4++){
        float xr[4][4];
#pragma unroll
        for (int nd = 0; nd < 4; nd++){
            float4 t = x4[(long long)(n0 + nd) * K4 + k4];
            xr[nd][0] = t.x; xr[nd][1] = t.y; xr[nd][2] = t.z; xr[nd][3] = t.w;
        }
        float wr[4][4];
#pragma unroll
        for (int j = 0; j < 4; j++){
            float4 t = W4[(long long)(k4 * 4 + j) * QC + q];
            wr[j][0] = t.x; wr[j][1] = t.y; wr[j][2] = t.z; wr[j][3] = t.w;
        }
#pragma unroll
        for (int nd = 0; nd < 4; nd++)
#pragma unroll
            for (int j = 0; j < 4; j++)
#pragma unroll
                for (int c = 0; c < 4; c++)
                    acc[nd][c] += xr[nd][j] * wr[j][c];
    }
    if (!POOL){
        float4* o4 = (float4*)outp;
#pragma unroll
        for (int nd = 0; nd < 4; nd++){
            o4[(long long)(n0 + nd) * QC + q] =
                make_float4(gelu_f(acc[nd][0]), gelu_f(acc[nd][1]),
                            gelu_f(acc[nd][2]), gelu_f(acc[nd][3]));
        }
    } else {
        int cur = batch[n0];
        float p0 = 0.f, p1 = 0.f, p2 = 0.f, p3 = 0.f, cloc = 0.f;
        int c0 = q * 4;
#pragma unroll
        for (int nd = 0; nd < 4; nd++){
            int gr = batch[n0 + nd];
            if (gr != cur){
                atomicAdd(&pool[cur * COUT + c0 + 0], p0);
                atomicAdd(&pool[cur * COUT + c0 + 1], p1);
                atomicAdd(&pool[cur * COUT + c0 + 2], p2);
                atomicAdd(&pool[cur * COUT + c0 + 3], p3);
                if (q == 0) atomicAdd(&cnt[cur], cloc);
                p0 = p1 = p2 = p3 = 0.f; cloc = 0.f; cur = gr;
            }
            p0 += gelu_f(acc[nd][0]); p1 += gelu_f(acc[nd][1]);
            p2 += gelu_f(acc[nd][2]); p3 += gelu_f(acc[nd][3]);
            cloc += 1.f;
        }
        atomicAdd(&pool[cur * COUT + c0 + 0], p0);
        atomicAdd(&pool[cur * COUT + c0 + 1], p1);
        atomicAdd(&pool[cur * COUT + c0 + 2], p2);
        atomicAdd(&pool[cur * COUT + c0 + 3], p3);
        if (q == 0) atomicAdd(&cnt[cur], cloc);
    }
}

// ---------------- BN stats: 128-block grid-stride streaming reduction ----------------
template<int C>
__global__ __launch_bounds__(256) void k_stats(const float* __restrict__ h, float* __restrict__ stat, int n){
    constexpr int REP = 256 / C;
    int t = threadIdx.x;
    int rep = t / C;
    int c = t % C;
    float s = 0.f, q = 0.f;
    for (int row = blockIdx.x * REP + rep; row < n; row += gridDim.x * REP){
        float v = h[(long long)row * C + c];
        s += v; q += v * v;
    }
    __shared__ float ss[256], sq[256];
    ss[t] = s; sq[t] = q;
    __syncthreads();
    for (int off = 128; off >= C; off >>= 1){
        if (t < off){ ss[t] += ss[t + off]; sq[t] += sq[t + off]; }
        __syncthreads();
    }
    if (t < C){
        atomicAdd(&stat[t], ss[t]);
        atomicAdd(&stat[128 + t], sq[t]);
    }
}

// ---------------- MLP head: 256 graphs, one block each ----------------
__global__ __launch_bounds__(128) void k_mlp(const float* __restrict__ pool, const float* __restrict__ cnt,
                                             const float* __restrict__ yex,
                                             const float* __restrict__ lw1, const float* __restrict__ lb1,
                                             const float* __restrict__ lw2, const float* __restrict__ lb2,
                                             const float* __restrict__ lw3, const float* __restrict__ lb3,
                                             const float* __restrict__ lw4, const float* __restrict__ lb4,
                                             float* __restrict__ outp){
    int g = blockIdx.x;
    int t = threadIdx.x;
    __shared__ float z[136];
    __shared__ float z2[128];
    __shared__ float z3[64];
    __shared__ float z4[32];
    float cdiv = fmaxf(cnt[g], 1.0f);
    z[t] = pool[g * 128 + t] / cdiv;
    if (t < 7) z[128 + t] = yex[g * 7 + t];
    __syncthreads();
    {   // 135 -> 128
        float acc = lb1[t];
        for (int k = 0; k < 135; k++) acc += z[k] * lw1[k * 128 + t];
        z2[t] = gelu_f(acc);
    }
    __syncthreads();
    if (t < 64){   // 128 -> 64
        float acc = lb2[t];
        for (int k = 0; k < 128; k++) acc += z2[k] * lw2[k * 64 + t];
        z3[t] = gelu_f(acc);
    }
    __syncthreads();
    if (t < 32){   // 64 -> 32
        float acc = lb3[t];
        for (int k = 0; k < 64; k++) acc += z3[k] * lw3[k * 32 + t];
        z4[t] = gelu_f(acc);
    }
    __syncthreads();
    if (t < 2){    // 32 -> 2, sigmoid
        float acc = lb4[t];
        for (int k = 0; k < 32; k++) acc += z4[k] * lw4[k * 2 + t];
        outp[g * 2 + t] = 1.0f / (1.0f + expf(-acc));
    }
}

extern "C" void kernel_launch(void* const* d_in, const int* in_sizes, int n_in,
                              void* d_out, int out_size, void* d_ws, size_t ws_size,
                              hipStream_t stream) {
    const float* x     = (const float*)d_in[0];
    const int*   ei    = (const int*)  d_in[1];   // [2, E]: src = ei, dst = ei+E
    const int*   batch = (const int*)  d_in[2];
    const float* yex   = (const float*)d_in[3];
    const float* W1 = (const float*)d_in[4];  const float* b1 = (const float*)d_in[5];
    const float* W2 = (const float*)d_in[6];  const float* b2 = (const float*)d_in[7];
    const float* W3 = (const float*)d_in[8];  const float* b3 = (const float*)d_in[9];
    const float* W4 = (const float*)d_in[10]; const float* b4 = (const float*)d_in[11];
    const float* g1 = (const float*)d_in[12]; const float* be1 = (const float*)d_in[13];
    const float* g2 = (const float*)d_in[14]; const float* be2 = (const float*)d_in[15];
    const float* g3 = (const float*)d_in[16]; const float* be3 = (const float*)d_in[17];
    const float* lw1 = (const float*)d_in[18]; const float* lb1 = (const float*)d_in[19];
    const float* lw2 = (const float*)d_in[20]; const float* lb2 = (const float*)d_in[21];
    const float* lw3 = (const float*)d_in[22]; const float* lb3 = (const float*)d_in[23];
    const float* lw4 = (const float*)d_in[24]; const float* lb4 = (const float*)d_in[25];
    float* out = (float*)d_out;

    // ---- workspace carve (256B-aligned); zero-region first ----
    char* wsb = (char*)d_ws;
    size_t off = 0;
    auto alloc = [&](size_t elems) -> void* {
        void* p = wsb + off;
        off += ((elems * 4 + 255) / 256) * 256;
        return p;
    };
    int*   deg    = (int*)  alloc(NN);
    float* stats  = (float*)alloc(3 * 256);      // layer l: [l*256+c]=sum, [l*256+128+c]=sumsq
    float* pool   = (float*)alloc(GG * 128);
    float* cntv   = (float*)alloc(GG);
    float* agg1   = (float*)alloc(NN);
    size_t zero_bytes = off;
    int*   rp     = (int*)  alloc(NN + 1);
    int*   cursor = (int*)  alloc(NN);
    float* dis    = (float*)alloc(NN);
    int*   bsum   = (int*)  alloc(NB_SCAN);
    int*   boff   = (int*)  alloc(NB_SCAN);
    int*   col    = (int*)  alloc(EE);
    float* wn     = (float*)alloc(EE);
    float* hbuf   = (float*)alloc((size_t)NN * 64);   // raw gelu outputs (<=64 ch)
    float* abuf   = (float*)alloc((size_t)NN * 64);   // aggregated inputs (<=64 ch)

    hipMemsetAsync(d_ws, 0, zero_bytes, stream);

    auto nb = [](long long total){ return (int)((total + 255) / 256); };

    // ---- graph norm precompute (parallel scan) ----
    k_deg  <<<nb(EE), 256, 0, stream>>>(ei + EE, deg, EE);
    k_bsum <<<NB_SCAN, 256, 0, stream>>>(deg, bsum, NN);
    k_pscan<<<1, 256, 0, stream>>>(bsum, boff, rp, NB_SCAN, NN);
    k_apply<<<NB_SCAN, 256, 0, stream>>>(deg, boff, rp, cursor, dis, NN);
    k_fill <<<nb(EE), 256, 0, stream>>>(ei, ei + EE, dis, cursor, col, wn, EE);

    // ---- layer 1: aggregate x (C=1), 1->16 linear+gelu, stats ----
    k_agg1<<<nb(EE + NN), 256, 0, stream>>>(x, ei, ei + EE, dis, agg1, EE, NN);
    k_lin1<<<nb((long long)NN * 16), 256, 0, stream>>>(agg1, W1, b1, hbuf, NN);
    k_stats<16><<<128, 256, 0, stream>>>(hbuf, stats + 0, NN);

    // ---- layer 2: gather h1 (BN1 inline), 16->32 reg-blocked linear+gelu, stats ----
    k_gather<16><<<nb((long long)NN * 4), 256, 0, stream>>>(hbuf, rp, col, wn, dis, stats + 0, g1, be1, abuf, NN);
    k_lin4<16, 32, false><<<nb((long long)(NN / 4) * 8), 256, 0, stream>>>(abuf, W2, b2, hbuf, nullptr, nullptr, nullptr, NN);
    k_stats<32><<<128, 256, 0, stream>>>(hbuf, stats + 256, NN);

    // ---- layer 3: gather h2 (BN2 inline), 32->64 reg-blocked linear+gelu, stats ----
    k_gather<32><<<nb((long long)NN * 8), 256, 0, stream>>>(hbuf, rp, col, wn, dis, stats + 256, g2, be2, abuf, NN);
    k_lin4<32, 64, false><<<nb((long long)(NN / 4) * 16), 256, 0, stream>>>(abuf, W3, b3, hbuf, nullptr, nullptr, nullptr, NN);
    k_stats<64><<<128, 256, 0, stream>>>(hbuf, stats + 512, NN);

    // ---- layer 4: gather h3 (BN3 inline), fused 64->128 reg-blocked linear+gelu+pool ----
    k_gather<64><<<nb((long long)NN * 16), 256, 0, stream>>>(hbuf, rp, col, wn, dis, stats + 512, g3, be3, abuf, NN);
    k_lin4<64, 128, true><<<nb((long long)(NN / 4) * 32), 256, 0, stream>>>(abuf, W4, b4, nullptr, batch, pool, cntv, NN);

    // ---- MLP head ----
    k_mlp<<<GG, 128, 0, stream>>>(pool, cntv, yex,
                                  lw1, lb1, lw2, lb2, lw3, lb3, lw4, lb4, out);
}

// Round 7
// 457.395 us; speedup vs baseline: 1.1676x; 1.0313x over previous
//
#include <hip/hip_runtime.h>
#include <math.h>

#define NN 50000
#define EE 800000
#define GG 256
#define NB_SCAN 196   // ceil(50000/256)

__device__ __forceinline__ float gelu_f(float v){
    return 0.5f * v * (1.0f + erff(v * 0.70710678118654752f));
}

// ---------------- degree count over dst ----------------
__global__ __launch_bounds__(256) void k_deg(const int* __restrict__ dst, int* __restrict__ deg, int e){
    int i = blockIdx.x * blockDim.x + threadIdx.x;
    if (i < e) atomicAdd(&deg[dst[i]], 1);
}

// ---------------- scan phase 1: per-block sums ----------------
__global__ __launch_bounds__(256) void k_bsum(const int* __restrict__ deg, int* __restrict__ bsum, int n){
    __shared__ int s[256];
    int t = threadIdx.x;
    int i = blockIdx.x * 256 + t;
    s[t] = (i < n) ? deg[i] : 0;
    __syncthreads();
    for (int off = 128; off > 0; off >>= 1){
        if (t < off) s[t] += s[t + off];
        __syncthreads();
    }
    if (t == 0) bsum[blockIdx.x] = s[0];
}

// ---------------- scan phase 2: single-block scan of partials ----------------
__global__ __launch_bounds__(256) void k_pscan(const int* __restrict__ bsum, int* __restrict__ boff,
                                               int* __restrict__ rp, int nb, int n){
    __shared__ int s[256];
    int t = threadIdx.x;
    int v = (t < nb) ? bsum[t] : 0;
    s[t] = v;
    __syncthreads();
    for (int off = 1; off < 256; off <<= 1){
        int u = (t >= off) ? s[t - off] : 0;
        __syncthreads();
        s[t] += u;
        __syncthreads();
    }
    if (t < nb) boff[t] = s[t] - v;          // exclusive block offset
    if (t == nb - 1) rp[n] = s[t];           // total (= E)
}

// ---------------- scan phase 3: apply ----------------
__global__ __launch_bounds__(256) void k_apply(const int* __restrict__ deg, const int* __restrict__ boff,
                                               int* __restrict__ rp, int* __restrict__ cursor,
                                               float* __restrict__ dis, int n){
    __shared__ int s[256];
    int t = threadIdx.x;
    int i = blockIdx.x * 256 + t;
    int d = (i < n) ? deg[i] : 0;
    s[t] = d;
    __syncthreads();
    for (int off = 1; off < 256; off <<= 1){
        int u = (t >= off) ? s[t - off] : 0;
        __syncthreads();
        s[t] += u;
        __syncthreads();
    }
    if (i < n){
        int excl = s[t] - d + boff[blockIdx.x];
        rp[i] = excl;
        cursor[i] = excl;
        dis[i] = rsqrtf((float)(d + 1));     // +1 self loop
    }
}

// ---------------- CSR fill ----------------
__global__ __launch_bounds__(256) void k_fill(const int* __restrict__ src, const int* __restrict__ dst,
                                              const float* __restrict__ dis, int* __restrict__ cursor,
                                              int* __restrict__ col, float* __restrict__ wn, int e){
    int i = blockIdx.x * blockDim.x + threadIdx.x;
    if (i < e){
        int d = dst[i], s = src[i];
        int p = atomicAdd(&cursor[d], 1);
        col[p] = s;
        wn[p]  = dis[s] * dis[d];
    }
}

// ---------------- layer-1 aggregation of x (C=1): edge-parallel atomics + self loop ----------------
__global__ __launch_bounds__(256) void k_agg1(const float* __restrict__ x, const int* __restrict__ src,
                                              const int* __restrict__ dst, const float* __restrict__ dis,
                                              float* __restrict__ agg, int e, int n){
    int i = blockIdx.x * blockDim.x + threadIdx.x;
    if (i < e){
        int s = src[i], d = dst[i];
        atomicAdd(&agg[d], x[s] * dis[s] * dis[d]);
    } else if (i < e + n){
        int node = i - e;
        float dn = dis[node];
        atomicAdd(&agg[node], dn * dn * x[node]);
    }
}

// ---------------- gather with inline BN of previous layer (float4, 4-edge unroll) ----------------
template<int C>
__global__ __launch_bounds__(256) void k_gather(const float* __restrict__ h, const int* __restrict__ rp,
                                                const int* __restrict__ col, const float* __restrict__ wn,
                                                const float* __restrict__ dis, const float* __restrict__ stat,
                                                const float* __restrict__ gamma, const float* __restrict__ beta,
                                                float* __restrict__ outp, int n){
    constexpr int TPN = C / 4;
    int i = blockIdx.x * 256 + threadIdx.x;
    int node = i / TPN, q = i % TPN;
    if (node >= n) return;
    int c0 = q * 4;
    const float invn = 1.0f / (float)NN;
    float scv[4], shv[4];
#pragma unroll
    for (int u = 0; u < 4; u++){
        float mean = stat[c0 + u] * invn;
        float var  = stat[128 + c0 + u] * invn - mean * mean;
        float sc   = gamma[c0 + u] * rsqrtf(var + 1e-5f);
        scv[u] = sc;
        shv[u] = beta[c0 + u] - mean * sc;
    }
    const float4* h4 = (const float4*)h;
    int beg = rp[node], end = rp[node + 1];
    float a0 = 0.f, a1 = 0.f, a2 = 0.f, a3 = 0.f;   // raw weighted sums (BN applied affinely at end)
    float b0 = 0.f, b1 = 0.f, b2 = 0.f, b3 = 0.f;
    float wsum_a = 0.f, wsum_b = 0.f;
    int j = beg;
    for (; j + 3 < end; j += 4){
        int   i0 = col[j], i1 = col[j+1], i2 = col[j+2], i3 = col[j+3];
        float w0 = wn[j], w1 = wn[j+1], w2 = wn[j+2], w3 = wn[j+3];
        float4 v0 = h4[i0 * TPN + q];
        float4 v1 = h4[i1 * TPN + q];
        float4 v2 = h4[i2 * TPN + q];
        float4 v3 = h4[i3 * TPN + q];
        a0 += v0.x*w0; a1 += v0.y*w0; a2 += v0.z*w0; a3 += v0.w*w0; wsum_a += w0;
        b0 += v1.x*w1; b1 += v1.y*w1; b2 += v1.z*w1; b3 += v1.w*w1; wsum_b += w1;
        a0 += v2.x*w2; a1 += v2.y*w2; a2 += v2.z*w2; a3 += v2.w*w2; wsum_a += w2;
        b0 += v3.x*w3; b1 += v3.y*w3; b2 += v3.z*w3; b3 += v3.w*w3; wsum_b += w3;
    }
    for (; j < end; j++){
        float w = wn[j];
        float4 v = h4[col[j] * TPN + q];
        a0 += v.x*w; a1 += v.y*w; a2 += v.z*w; a3 += v.w*w; wsum_a += w;
    }
    float dn = dis[node];
    float ws = dn * dn;
    float4 vs = h4[node * TPN + q];
    a0 += vs.x*ws; a1 += vs.y*ws; a2 += vs.z*ws; a3 += vs.w*ws; wsum_a += ws;
    a0 += b0; a1 += b1; a2 += b2; a3 += b3;
    float wsum = wsum_a + wsum_b;
    float4 r = make_float4(a0 * scv[0] + shv[0] * wsum,
                           a1 * scv[1] + shv[1] * wsum,
                           a2 * scv[2] + shv[2] * wsum,
                           a3 * scv[3] + shv[3] * wsum);
    ((float4*)outp)[node * TPN + q] = r;
}

// ---------------- 1->16 linear + bias + GELU (x is a single channel) ----------------
__global__ __launch_bounds__(256) void k_lin1(const float* __restrict__ xin, const float* __restrict__ W,
                                              const float* __restrict__ bias, float* __restrict__ outp, int n){
    int i = blockIdx.x * 256 + threadIdx.x;
    int node = i / 16, c = i % 16;
    if (node >= n) return;
    outp[i] = gelu_f(bias[c] + xin[node] * W[c]);
}

// ---------------- dense linear + bias + GELU: 2 nodes x 4 channels per thread ----------------
// Small fixed live set (~32 floats) so the allocator lands at ~60 VGPR without caps.
// unroll 1: 6 independent float4 loads per iter give ILP; TLP from high occupancy.
template<int CIN, int COUT>
__global__ __launch_bounds__(256) void k_linT(const float* __restrict__ xin, const float* __restrict__ W,
                                              const float* __restrict__ bias, float* __restrict__ outp, int n){
    constexpr int QC = COUT / 4;      // float4 channel groups
    constexpr int K4 = CIN / 4;       // float4 K groups
    int i = blockIdx.x * 256 + threadIdx.x;
    int pair = i / QC, q = i % QC;
    int n0 = pair * 2;                 // NN % 2 == 0
    if (n0 >= n) return;
    const float4* xa = (const float4*)(xin + (size_t)n0 * CIN);
    const float4* xb = (const float4*)(xin + (size_t)(n0 + 1) * CIN);
    const float4* Wq = (const float4*)W + q;      // row k at Wq[k * QC]
    float4 bb = ((const float4*)bias)[q];
    float aA0 = bb.x, aA1 = bb.y, aA2 = bb.z, aA3 = bb.w;
    float aB0 = bb.x, aB1 = bb.y, aB2 = bb.z, aB3 = bb.w;
#pragma unroll 1
    for (int k4 = 0; k4 < K4; k4++){
        float4 xA = xa[k4];
        float4 xB = xb[k4];
        float4 w0 = Wq[(k4 * 4 + 0) * QC];
        float4 w1 = Wq[(k4 * 4 + 1) * QC];
        float4 w2 = Wq[(k4 * 4 + 2) * QC];
        float4 w3 = Wq[(k4 * 4 + 3) * QC];
        aA0 += xA.x*w0.x + xA.y*w1.x + xA.z*w2.x + xA.w*w3.x;
        aA1 += xA.x*w0.y + xA.y*w1.y + xA.z*w2.y + xA.w*w3.y;
        aA2 += xA.x*w0.z + xA.y*w1.z + xA.z*w2.z + xA.w*w3.z;
        aA3 += xA.x*w0.w + xA.y*w1.w + xA.z*w2.w + xA.w*w3.w;
        aB0 += xB.x*w0.x + xB.y*w1.x + xB.z*w2.x + xB.w*w3.x;
        aB1 += xB.x*w0.y + xB.y*w1.y + xB.z*w2.y + xB.w*w3.y;
        aB2 += xB.x*w0.z + xB.y*w1.z + xB.z*w2.z + xB.w*w3.z;
        aB3 += xB.x*w0.w + xB.y*w1.w + xB.z*w2.w + xB.w*w3.w;
    }
    float4* o4 = (float4*)outp;
    o4[(size_t)n0 * QC + q]       = make_float4(gelu_f(aA0), gelu_f(aA1), gelu_f(aA2), gelu_f(aA3));
    o4[(size_t)(n0 + 1) * QC + q] = make_float4(gelu_f(aB0), gelu_f(aB1), gelu_f(aB2), gelu_f(aB3));
}

// ---------------- BN stats: 128-block grid-stride streaming reduction ----------------
template<int C>
__global__ __launch_bounds__(256) void k_stats(const float* __restrict__ h, float* __restrict__ stat, int n){
    constexpr int REP = 256 / C;
    int t = threadIdx.x;
    int rep = t / C;
    int c = t % C;
    float s = 0.f, q = 0.f;
    for (int row = blockIdx.x * REP + rep; row < n; row += gridDim.x * REP){
        float v = h[(long long)row * C + c];
        s += v; q += v * v;
    }
    __shared__ float ss[256], sq[256];
    ss[t] = s; sq[t] = q;
    __syncthreads();
    for (int off = 128; off >= C; off >>= 1){
        if (t < off){ ss[t] += ss[t + off]; sq[t] += sq[t + off]; }
        __syncthreads();
    }
    if (t < C){
        atomicAdd(&stat[t], ss[t]);
        atomicAdd(&stat[128 + t], sq[t]);
    }
}

// ---------------- mean-pool: one block per graph, binary search sorted batch, no atomics ----------------
__global__ __launch_bounds__(128) void k_pool(const float* __restrict__ h4, const int* __restrict__ batch,
                                              float* __restrict__ pool, int n){
    int g = blockIdx.x;
    int t = threadIdx.x;
    // first index with batch[idx] >= g
    int lo = 0, hi = n;
    while (lo < hi){ int mid = (lo + hi) >> 1; if (batch[mid] < g) lo = mid + 1; else hi = mid; }
    int s = lo;
    // first index with batch[idx] >= g+1
    hi = n;
    while (lo < hi){ int mid = (lo + hi) >> 1; if (batch[mid] < g + 1) lo = mid + 1; else hi = mid; }
    int e = lo;
    float a0 = 0.f, a1 = 0.f, a2 = 0.f, a3 = 0.f;
    int node = s;
    for (; node + 3 < e; node += 4){
        a0 += h4[(size_t)(node + 0) * 128 + t];
        a1 += h4[(size_t)(node + 1) * 128 + t];
        a2 += h4[(size_t)(node + 2) * 128 + t];
        a3 += h4[(size_t)(node + 3) * 128 + t];
    }
    for (; node < e; node++) a0 += h4[(size_t)node * 128 + t];
    float sum = (a0 + a1) + (a2 + a3);
    pool[g * 128 + t] = sum / fmaxf((float)(e - s), 1.0f);
}

// ---------------- MLP head: 256 graphs, one block each (pool already holds means) ----------------
__global__ __launch_bounds__(128) void k_mlp(const float* __restrict__ pool,
                                             const float* __restrict__ yex,
                                             const float* __restrict__ lw1, const float* __restrict__ lb1,
                                             const float* __restrict__ lw2, const float* __restrict__ lb2,
                                             const float* __restrict__ lw3, const float* __restrict__ lb3,
                                             const float* __restrict__ lw4, const float* __restrict__ lb4,
                                             float* __restrict__ outp){
    int g = blockIdx.x;
    int t = threadIdx.x;
    __shared__ float z[136];
    __shared__ float z2[128];
    __shared__ float z3[64];
    __shared__ float z4[32];
    z[t] = pool[g * 128 + t];
    if (t < 7) z[128 + t] = yex[g * 7 + t];
    __syncthreads();
    {   // 135 -> 128
        float acc = lb1[t];
        for (int k = 0; k < 135; k++) acc += z[k] * lw1[k * 128 + t];
        z2[t] = gelu_f(acc);
    }
    __syncthreads();
    if (t < 64){   // 128 -> 64
        float acc = lb2[t];
        for (int k = 0; k < 128; k++) acc += z2[k] * lw2[k * 64 + t];
        z3[t] = gelu_f(acc);
    }
    __syncthreads();
    if (t < 32){   // 64 -> 32
        float acc = lb3[t];
        for (int k = 0; k < 64; k++) acc += z3[k] * lw3[k * 32 + t];
        z4[t] = gelu_f(acc);
    }
    __syncthreads();
    if (t < 2){    // 32 -> 2, sigmoid
        float acc = lb4[t];
        for (int k = 0; k < 32; k++) acc += z4[k] * lw4[k * 2 + t];
        outp[g * 2 + t] = 1.0f / (1.0f + expf(-acc));
    }
}

extern "C" void kernel_launch(void* const* d_in, const int* in_sizes, int n_in,
                              void* d_out, int out_size, void* d_ws, size_t ws_size,
                              hipStream_t stream) {
    const float* x     = (const float*)d_in[0];
    const int*   ei    = (const int*)  d_in[1];   // [2, E]: src = ei, dst = ei+E
    const int*   batch = (const int*)  d_in[2];
    const float* yex   = (const float*)d_in[3];
    const float* W1 = (const float*)d_in[4];  const float* b1 = (const float*)d_in[5];
    const float* W2 = (const float*)d_in[6];  const float* b2 = (const float*)d_in[7];
    const float* W3 = (const float*)d_in[8];  const float* b3 = (const float*)d_in[9];
    const float* W4 = (const float*)d_in[10]; const float* b4 = (const float*)d_in[11];
    const float* g1 = (const float*)d_in[12]; const float* be1 = (const float*)d_in[13];
    const float* g2 = (const float*)d_in[14]; const float* be2 = (const float*)d_in[15];
    const float* g3 = (const float*)d_in[16]; const float* be3 = (const float*)d_in[17];
    const float* lw1 = (const float*)d_in[18]; const float* lb1 = (const float*)d_in[19];
    const float* lw2 = (const float*)d_in[20]; const float* lb2 = (const float*)d_in[21];
    const float* lw3 = (const float*)d_in[22]; const float* lb3 = (const float*)d_in[23];
    const float* lw4 = (const float*)d_in[24]; const float* lb4 = (const float*)d_in[25];
    float* out = (float*)d_out;

    // ---- workspace carve (256B-aligned); zero-region first ----
    char* wsb = (char*)d_ws;
    size_t off = 0;
    auto alloc = [&](size_t elems) -> void* {
        void* p = wsb + off;
        off += ((elems * 4 + 255) / 256) * 256;
        return p;
    };
    int*   deg    = (int*)  alloc(NN);
    float* stats  = (float*)alloc(3 * 256);      // layer l: [l*256+c]=sum, [l*256+128+c]=sumsq
    float* agg1   = (float*)alloc(NN);
    size_t zero_bytes = off;
    float* pool   = (float*)alloc(GG * 128);
    int*   rp     = (int*)  alloc(NN + 1);
    int*   cursor = (int*)  alloc(NN);
    float* dis    = (float*)alloc(NN);
    int*   bsum   = (int*)  alloc(NB_SCAN);
    int*   boff   = (int*)  alloc(NB_SCAN);
    int*   col    = (int*)  alloc(EE);
    float* wn     = (float*)alloc(EE);
    float* hbuf   = (float*)alloc((size_t)NN * 128);  // gelu outputs (16/32/64ch reuse; 128ch for L4)
    float* abuf   = (float*)alloc((size_t)NN * 64);   // aggregated inputs (<=64 ch)

    hipMemsetAsync(d_ws, 0, zero_bytes, stream);

    auto nb = [](long long total){ return (int)((total + 255) / 256); };

    // ---- graph norm precompute (parallel scan) ----
    k_deg  <<<nb(EE), 256, 0, stream>>>(ei + EE, deg, EE);
    k_bsum <<<NB_SCAN, 256, 0, stream>>>(deg, bsum, NN);
    k_pscan<<<1, 256, 0, stream>>>(bsum, boff, rp, NB_SCAN, NN);
    k_apply<<<NB_SCAN, 256, 0, stream>>>(deg, boff, rp, cursor, dis, NN);
    k_fill <<<nb(EE), 256, 0, stream>>>(ei, ei + EE, dis, cursor, col, wn, EE);

    // ---- layer 1: aggregate x (C=1), 1->16 linear+gelu, stats ----
    k_agg1<<<nb(EE + NN), 256, 0, stream>>>(x, ei, ei + EE, dis, agg1, EE, NN);
    k_lin1<<<nb((long long)NN * 16), 256, 0, stream>>>(agg1, W1, b1, hbuf, NN);
    k_stats<16><<<128, 256, 0, stream>>>(hbuf, stats + 0, NN);

    // ---- layer 2: gather h1 (BN1 inline), 16->32 linear+gelu, stats ----
    k_gather<16><<<nb((long long)NN * 4), 256, 0, stream>>>(hbuf, rp, col, wn, dis, stats + 0, g1, be1, abuf, NN);
    k_linT<16, 32><<<nb((long long)(NN / 2) * 8), 256, 0, stream>>>(abuf, W2, b2, hbuf, NN);
    k_stats<32><<<128, 256, 0, stream>>>(hbuf, stats + 256, NN);

    // ---- layer 3: gather h2 (BN2 inline), 32->64 linear+gelu, stats ----
    k_gather<32><<<nb((long long)NN * 8), 256, 0, stream>>>(hbuf, rp, col, wn, dis, stats + 256, g2, be2, abuf, NN);
    k_linT<32, 64><<<nb((long long)(NN / 2) * 16), 256, 0, stream>>>(abuf, W3, b3, hbuf, NN);
    k_stats<64><<<128, 256, 0, stream>>>(hbuf, stats + 512, NN);

    // ---- layer 4: gather h3 (BN3 inline), 64->128 linear+gelu, then block-per-graph mean pool ----
    k_gather<64><<<nb((long long)NN * 16), 256, 0, stream>>>(hbuf, rp, col, wn, dis, stats + 512, g3, be3, abuf, NN);
    k_linT<64, 128><<<nb((long long)(NN / 2) * 32), 256, 0, stream>>>(abuf, W4, b4, hbuf, NN);
    k_pool<<<GG, 128, 0, stream>>>(hbuf, batch, pool, NN);

    // ---- MLP head ----
    k_mlp<<<GG, 128, 0, stream>>>(pool, yex,
                                  lw1, lb1, lw2, lb2, lw3, lb3, lw4, lb4, out);
}